// Round 4
// baseline (213.784 us; speedup 1.0000x reference)
//
#include <hip/hip_runtime.h>
#include <math.h>
#include <stdint.h>

#define NN 8192
#define HID 1024
#define PROJ 128

constexpr float INV_T = 1.0f / 0.07f;
constexpr float LN_EPS = 1e-12f;
// exp((d-m)/T) = exp2((d-m)*CC)
constexpr float CC = 14.285714285714286f * 1.4426950408889634f;

typedef __bf16 bf16x8 __attribute__((ext_vector_type(8)));
typedef float f32x4 __attribute__((ext_vector_type(4)));

#define EXP2(x) __builtin_amdgcn_exp2f(x)

#define GLD16(g, l)                                                     \
  __builtin_amdgcn_global_load_lds(                                     \
      (const __attribute__((address_space(1))) uint32_t*)(g),           \
      (__attribute__((address_space(3))) uint32_t*)(l), 16, 0, 0)

__device__ __forceinline__ uint16_t f2bf(float f) {
  union { float f; uint32_t u; } c; c.f = f;
  uint32_t r = (c.u + 0x7FFFu + ((c.u >> 16) & 1u)) >> 16;
  return (uint16_t)r;
}
__device__ __forceinline__ float bf2f(uint16_t u) {
  union { uint32_t u; float f; } c; c.u = ((uint32_t)u) << 16;
  return c.f;
}

// gelu(v) ~= v * sigmoid(2u), u = 0.79788456(v + 0.044715 v^3)
__device__ __forceinline__ float gelu_f(float v) {
  float w = v * v;
  float u = v * fmaf(w, 0.0356774081f, 0.7978845608f);
  float e = EXP2(u * -2.8853900818f);
  return v * __builtin_amdgcn_rcpf(1.0f + e);
}

// ------------- convert fp32 -> bf16; also zero stats/c_e buffers ----------
__global__ __launch_bounds__(256) void k_conv(const float* __restrict__ in,
                                              uint16_t* __restrict__ out,
                                              float* __restrict__ sums,
                                              float* __restrict__ c_e) {
  const int b = blockIdx.x, t = threadIdx.x;
  if (b < 64) sums[b * 256 + t] = 0.f;       // sum[8192] + sumsq[8192]
  else if (b == 64) c_e[t] = 0.f;            // c[128] + e[128]
  int i = (b * 256 + t) * 4;
  float4 v = *(const float4*)(in + i);
  ushort4 o;
  o.x = f2bf(v.x); o.y = f2bf(v.y); o.z = f2bf(v.z); o.w = f2bf(v.w);
  *(ushort4*)(out + i) = o;
}

// ------------- transpose+convert: fp32 [R][C] -> bf16 [C][R] --------------
__global__ __launch_bounds__(256) void k_t1(const float* __restrict__ in,
                                            uint16_t* __restrict__ out,
                                            int R, int C) {
  __shared__ uint16_t t[32][33];
  const int cb = blockIdx.x * 32, rb = blockIdx.y * 32;
  const int tr = threadIdx.x >> 3, tc4 = (threadIdx.x & 7) * 4;
  float4 v = *(const float4*)(in + (size_t)(rb + tr) * C + cb + tc4);
  t[tc4 + 0][tr] = f2bf(v.x);
  t[tc4 + 1][tr] = f2bf(v.y);
  t[tc4 + 2][tr] = f2bf(v.z);
  t[tc4 + 3][tr] = f2bf(v.w);
  __syncthreads();
  const int oc = threadIdx.x >> 3, or4 = (threadIdx.x & 7) * 4;
  ushort4 o;
  o.x = t[oc][or4 + 0]; o.y = t[oc][or4 + 1];
  o.z = t[oc][or4 + 2]; o.w = t[oc][or4 + 3];
  *(ushort4*)(out + (size_t)(cb + oc) * R + rb + or4) = o;
}

// --- dec_w: transpose + fold gamma -> bf16 [128][1024]; column sums c,e ---
__global__ __launch_bounds__(256) void k_t2(const float* __restrict__ in,
                                            const float* __restrict__ gamma,
                                            const float* __restrict__ beta,
                                            uint16_t* __restrict__ out,
                                            float* __restrict__ c_e) {
  __shared__ float tg[32][33];
  __shared__ float tb[32][33];
  const int cb = blockIdx.x * 32, rb = blockIdx.y * 32;
  const int tr = threadIdx.x >> 3, tc4 = (threadIdx.x & 7) * 4;
  const float g = gamma[rb + tr], be = beta[rb + tr];
  float4 v = *(const float4*)(in + (size_t)(rb + tr) * PROJ + cb + tc4);
  tg[tc4 + 0][tr] = g * v.x;  tb[tc4 + 0][tr] = be * v.x;
  tg[tc4 + 1][tr] = g * v.y;  tb[tc4 + 1][tr] = be * v.y;
  tg[tc4 + 2][tr] = g * v.z;  tb[tc4 + 2][tr] = be * v.z;
  tg[tc4 + 3][tr] = g * v.w;  tb[tc4 + 3][tr] = be * v.w;
  __syncthreads();
  const int oc = threadIdx.x >> 3, or4 = (threadIdx.x & 7) * 4;
  ushort4 o;
  o.x = f2bf(tg[oc][or4 + 0]); o.y = f2bf(tg[oc][or4 + 1]);
  o.z = f2bf(tg[oc][or4 + 2]); o.w = f2bf(tg[oc][or4 + 3]);
  *(ushort4*)(out + (size_t)(cb + oc) * HID + rb + or4) = o;
  if (threadIdx.x < 32) {
    float sc = 0.f, se = 0.f;
#pragma unroll
    for (int d = 0; d < 32; ++d) { sc += tg[threadIdx.x][d]; se += tb[threadIdx.x][d]; }
    atomicAdd(c_e + cb + threadIdx.x, sc);
    atomicAdd(c_e + 128 + cb + threadIdx.x, se);
  }
}

// -------- GEMM1: h = gelu(x@W+b) bf16, + per-row sum/sumsq atomics --------
// 64x128 tile, BK=64 (two 32-k LDS panels, GLD16-compatible), grid (8,128).
__global__ __launch_bounds__(256) void k_gemm1(
    const uint16_t* __restrict__ Ab, const uint16_t* __restrict__ Bt,
    const float* __restrict__ bias, uint16_t* __restrict__ Hout,
    float* __restrict__ sums) {
  __shared__ __align__(16) uint16_t As[2 * 64 * 32];
  __shared__ __align__(16) uint16_t Bs[2 * 128 * 32];
  const int tid = threadIdx.x;
  const int bn = blockIdx.x * 128, bm = blockIdx.y * 64;
  const int wave = tid >> 6, lane = tid & 63;
  const int wx = wave & 1, wy = wave >> 1;
  const int col = lane & 15, quad = lane >> 4;
  f32x4 acc[2][4] = {};
  const char* Abase = (const char*)Ab;
  const char* Bbase = (const char*)Bt;
  for (int k0 = 0; k0 < HID; k0 += 64) {
    __syncthreads();
#pragma unroll
    for (int l = 0; l < 2; ++l) {
      int off = tid * 16 + l * 4096;
      int h = off >> 12, row = (off >> 6) & 63, inner = off & 63;
      GLD16(Abase + ((size_t)(bm + row) * HID + k0 + h * 32) * 2 + inner,
            (char*)As + off);
    }
#pragma unroll
    for (int l = 0; l < 4; ++l) {
      int off = tid * 16 + l * 4096;
      int h = off >> 13, row = (off >> 6) & 127, inner = off & 63;
      GLD16(Bbase + ((size_t)(bn + row) * HID + k0 + h * 32) * 2 + inner,
            (char*)Bs + off);
    }
    __syncthreads();
#pragma unroll
    for (int h = 0; h < 2; ++h) {
      bf16x8 a[2], b[4];
#pragma unroll
      for (int mt = 0; mt < 2; ++mt)
        a[mt] = *(const bf16x8*)&As[h * 2048 +
                                    (wy * 32 + mt * 16 + col) * 32 + quad * 8];
#pragma unroll
      for (int nt = 0; nt < 4; ++nt)
        b[nt] = *(const bf16x8*)&Bs[h * 4096 +
                                    (wx * 64 + nt * 16 + col) * 32 + quad * 8];
#pragma unroll
      for (int mt = 0; mt < 2; ++mt)
#pragma unroll
        for (int nt = 0; nt < 4; ++nt)
          acc[mt][nt] = __builtin_amdgcn_mfma_f32_16x16x32_bf16(
              a[mt], b[nt], acc[mt][nt], 0, 0, 0);
    }
  }
  float rsum[2][4] = {}, rsq[2][4] = {};
#pragma unroll
  for (int nt = 0; nt < 4; ++nt) {
    int gj = bn + wx * 64 + nt * 16 + col;
    float bv = bias[gj];
#pragma unroll
    for (int mt = 0; mt < 2; ++mt)
#pragma unroll
      for (int r = 0; r < 4; ++r) {
        int gi = bm + wy * 32 + mt * 16 + quad * 4 + r;
        float gl = gelu_f(acc[mt][nt][r] + bv);
        Hout[(size_t)gi * HID + gj] = f2bf(gl);
        rsum[mt][r] += gl;
        rsq[mt][r] = fmaf(gl, gl, rsq[mt][r]);
      }
  }
#pragma unroll
  for (int mt = 0; mt < 2; ++mt)
#pragma unroll
    for (int r = 0; r < 4; ++r) {
      float s1 = rsum[mt][r], s2 = rsq[mt][r];
#pragma unroll
      for (int off = 1; off < 16; off <<= 1) {
        s1 += __shfl_xor(s1, off, 64);
        s2 += __shfl_xor(s2, off, 64);
      }
      if (col == 0) {
        int gi = bm + wy * 32 + mt * 16 + quad * 4 + r;
        atomicAdd(&sums[gi], s1);
        atomicAdd(&sums[NN + gi], s2);
      }
    }
}

// --- GEMM2 with LN folded: z = r*(h@Wg) - r*mu*c + e + dec_b, bf16 out ----
__global__ __launch_bounds__(256) void k_gemm2(
    const uint16_t* __restrict__ Hb, const uint16_t* __restrict__ Wt2,
    const float* __restrict__ bd, const float* __restrict__ sums,
    const float* __restrict__ c_e, uint16_t* __restrict__ Z) {
  __shared__ __align__(16) uint16_t As2[32 * 32];
  __shared__ __align__(16) uint16_t Bs2[128 * 32];
  __shared__ float muS[32], rS[32];
  const int tid = threadIdx.x;
  const int bm = blockIdx.x * 32;
  const int wave = tid >> 6, lane = tid & 63;
  const int wx = wave & 1, wy = wave >> 1;
  const int col = lane & 15, quad = lane >> 4;
  if (tid < 32) {
    float s = sums[bm + tid], q = sums[NN + bm + tid];
    float mu = s * (1.0f / HID);
    float var = q * (1.0f / HID) - mu * mu;
    muS[tid] = mu;
    rS[tid] = rsqrtf(var + LN_EPS);
  }
  f32x4 acc[4] = {};
  const char* Abase = (const char*)Hb;
  const char* Bbase = (const char*)Wt2;
  for (int k0 = 0; k0 < HID; k0 += 32) {
    __syncthreads();
    if (tid < 128) {
      int off = tid * 16;
      int row = off >> 6, inner = off & 63;
      GLD16(Abase + ((size_t)(bm + row) * HID + k0) * 2 + inner,
            (char*)As2 + off);
    }
#pragma unroll
    for (int l = 0; l < 2; ++l) {
      int off = tid * 16 + l * 4096;
      int row = off >> 6, inner = off & 63;
      GLD16(Bbase + ((size_t)row * HID + k0) * 2 + inner, (char*)Bs2 + off);
    }
    __syncthreads();
    bf16x8 a = *(const bf16x8*)&As2[(wy * 16 + col) * 32 + quad * 8];
#pragma unroll
    for (int nt = 0; nt < 4; ++nt) {
      bf16x8 b = *(const bf16x8*)&Bs2[(wx * 64 + nt * 16 + col) * 32 + quad * 8];
      acc[nt] = __builtin_amdgcn_mfma_f32_16x16x32_bf16(a, b, acc[nt], 0, 0, 0);
    }
  }
#pragma unroll
  for (int nt = 0; nt < 4; ++nt) {
    int gj = wx * 64 + nt * 16 + col;
    float ck = c_e[gj], ek = c_e[128 + gj] + bd[gj];
#pragma unroll
    for (int r = 0; r < 4; ++r) {
      int li = wy * 16 + quad * 4 + r;
      float mu = muS[li], rr = rS[li];
      float z = fmaf(rr, acc[nt][r], fmaf(-rr * mu, ck, ek));
      Z[(size_t)(bm + li) * PROJ + gj] = f2bf(z);
    }
  }
}

// ------ flash logsumexp over Z Z^T: LDS-free, barrier-free waves ----------
// grid (64, 16): block = 4 indep waves x 32 i-rows; chunk = 512 j.
__device__ __forceinline__ void lse4(float& m, float& s, float v0, float v1,
                                     float v2, float v3) {
  float lm = fmaxf(fmaxf(v0, v1), fmaxf(v2, v3));
  float mn = fmaxf(m, lm);
  float tn = mn * CC;
  float rs = EXP2(fmaf(m, CC, -tn));
  float e = EXP2(fmaf(v0, CC, -tn)) + EXP2(fmaf(v1, CC, -tn)) +
            EXP2(fmaf(v2, CC, -tn)) + EXP2(fmaf(v3, CC, -tn));
  s = fmaf(s, rs, e);
  m = mn;
}

__global__ __launch_bounds__(256) void k_sim(const uint16_t* __restrict__ Z,
                                             float* __restrict__ m_part,
                                             float* __restrict__ s_part,
                                             float* __restrict__ pos_arr) {
  const int tid = threadIdx.x;
  const int wave = tid >> 6, lane = tid & 63;
  const int col = lane & 15, quad = lane >> 4;
  const int wrow0 = blockIdx.x * 128 + wave * 32;
  const int chunk = blockIdx.y;
  bf16x8 afr[2][4];
#pragma unroll
  for (int mt = 0; mt < 2; ++mt)
#pragma unroll
    for (int kc = 0; kc < 4; ++kc)
      afr[mt][kc] = *(const bf16x8*)(Z +
          (size_t)(wrow0 + mt * 16 + col) * PROJ + kc * 32 + quad * 8);
  float ms[8], ss[8];
#pragma unroll
  for (int i = 0; i < 8; ++i) { ms[i] = -INFINITY; ss[i] = 0.f; }
  const int diag_t = wrow0 & ~63;
  const int pos_t = ((wrow0 + NN / 2) & (NN - 1)) & ~63;
  const int jbase = chunk * 512;
  for (int t8 = 0; t8 < 8; ++t8) {
    const int jt = jbase + t8 * 64;
    f32x4 acc[2][4] = {};
#pragma unroll
    for (int kc = 0; kc < 4; ++kc) {
      bf16x8 b[4];
#pragma unroll
      for (int nt = 0; nt < 4; ++nt)
        b[nt] = *(const bf16x8*)(Z + (size_t)(jt + nt * 16 + col) * PROJ +
                                 kc * 32 + quad * 8);
#pragma unroll
      for (int mt = 0; mt < 2; ++mt)
#pragma unroll
        for (int nt = 0; nt < 4; ++nt)
          acc[mt][nt] = __builtin_amdgcn_mfma_f32_16x16x32_bf16(
              afr[mt][kc], b[nt], acc[mt][nt], 0, 0, 0);
    }
    if (jt != diag_t && jt != pos_t) {
#pragma unroll
      for (int mt = 0; mt < 2; ++mt)
#pragma unroll
        for (int r = 0; r < 4; ++r)
          lse4(ms[mt * 4 + r], ss[mt * 4 + r], acc[mt][0][r], acc[mt][1][r],
               acc[mt][2][r], acc[mt][3][r]);
    } else {
      const bool isd = (jt == diag_t);
#pragma unroll
      for (int mt = 0; mt < 2; ++mt)
#pragma unroll
        for (int r = 0; r < 4; ++r) {
          int gi = wrow0 + mt * 16 + quad * 4 + r;
          int partner = (gi + NN / 2) & (NN - 1);
          float v[4];
#pragma unroll
          for (int nt = 0; nt < 4; ++nt) {
            int gj = jt + nt * 16 + col;
            float d = acc[mt][nt][r];
            if (!isd && gj == partner) pos_arr[gi] = d;
            v[nt] = (isd && gj == gi) ? -INFINITY : d;
          }
          lse4(ms[mt * 4 + r], ss[mt * 4 + r], v[0], v[1], v[2], v[3]);
        }
    }
  }
#pragma unroll
  for (int ri = 0; ri < 8; ++ri) {
#pragma unroll
    for (int off = 1; off < 16; off <<= 1) {
      float om = __shfl_xor(ms[ri], off, 64);
      float os = __shfl_xor(ss[ri], off, 64);
      float mn = fmaxf(ms[ri], om);
      float tn = mn * CC;
      ss[ri] = fmaf(ss[ri], EXP2(fmaf(ms[ri], CC, -tn)),
                    os * EXP2(fmaf(om, CC, -tn)));
      ms[ri] = mn;
    }
  }
  if (col == 0) {
#pragma unroll
    for (int ri = 0; ri < 8; ++ri) {
      int gi = wrow0 + (ri >> 2) * 16 + quad * 4 + (ri & 3);
      m_part[(size_t)chunk * NN + gi] = ms[ri];
      s_part[(size_t)chunk * NN + gi] = ss[ri];
    }
  }
}

// ---------------- combine 16 chunk-partials per row ----------------
__global__ __launch_bounds__(256) void k_combine(
    const float* __restrict__ m_part, const float* __restrict__ s_part,
    const float* __restrict__ pos_arr, float* __restrict__ row_loss) {
  const int i = blockIdx.x * 256 + threadIdx.x;
  float M = -INFINITY;
#pragma unroll
  for (int p = 0; p < 16; ++p) M = fmaxf(M, m_part[(size_t)p * NN + i]);
  float S = 0.f;
  float t = M * CC;
#pragma unroll
  for (int p = 0; p < 16; ++p)
    S += s_part[(size_t)p * NN + i] * EXP2(fmaf(m_part[(size_t)p * NN + i], CC, -t));
  row_loss[i] = (M - pos_arr[i]) * INV_T + logf(S);
}

// ---------------- mean over rows ----------------
__global__ __launch_bounds__(256) void k_final(
    const float* __restrict__ row_loss, float* __restrict__ out) {
  const int tid = threadIdx.x;
  float s = 0.f;
#pragma unroll
  for (int l = 0; l < 32; ++l) s += row_loss[tid + l * 256];
#pragma unroll
  for (int off = 32; off > 0; off >>= 1) s += __shfl_down(s, off);
  __shared__ float red[4];
  const int wave = tid >> 6, lane = tid & 63;
  if (lane == 0) red[wave] = s;
  __syncthreads();
  if (tid == 0) out[0] = (red[0] + red[1] + red[2] + red[3]) * (1.0f / NN);
}

extern "C" void kernel_launch(void* const* d_in, const int* in_sizes, int n_in,
                              void* d_out, int out_size, void* d_ws,
                              size_t ws_size, hipStream_t stream) {
  const float* x       = (const float*)d_in[0];
  const float* dense_w = (const float*)d_in[1];
  const float* dense_b = (const float*)d_in[2];
  const float* ln_g    = (const float*)d_in[3];
  const float* ln_b    = (const float*)d_in[4];
  const float* dec_w   = (const float*)d_in[5];
  const float* dec_b   = (const float*)d_in[6];
  float* out = (float*)d_out;
  char* ws = (char*)d_ws;
  // Phase 1 (through gemm1): xb [0,16M), wt [16M,18M), h [18M,34M)
  // Phase 2 (after gemm1):   z  [0,2M),  m_part/s_part reuse wt region
  uint16_t* xb      = (uint16_t*)(ws);
  uint16_t* wt      = (uint16_t*)(ws + 16777216);
  uint16_t* h       = (uint16_t*)(ws + 18874368);
  uint16_t* z       = (uint16_t*)(ws);
  float*    m_part  = (float*)(ws + 16777216);     // 16*8192*4 = 512 KiB
  float*    s_part  = (float*)(ws + 17301504);     // 512 KiB
  uint16_t* wt2     = (uint16_t*)(ws + 35651584);  // 256 KiB [128][1024]
  float*    sums    = (float*)(ws + 35913728);     // 64 KiB: sum|sumsq
  float*    c_e     = (float*)(ws + 35979264);     // 1 KiB: c[128]|e[128]
  float*    pos_arr = (float*)(ws + 35980288);     // 32 KiB
  float*    row_loss= (float*)(ws + 36013056);     // 32 KiB

  k_conv<<<dim3(NN * HID / 1024), 256, 0, stream>>>(x, xb, sums, c_e);
  k_t1<<<dim3(32, 32), 256, 0, stream>>>(dense_w, wt, HID, HID);
  k_t2<<<dim3(PROJ / 32, HID / 32), 256, 0, stream>>>(dec_w, ln_g, ln_b, wt2,
                                                      c_e);
  k_gemm1<<<dim3(8, 128), 256, 0, stream>>>(xb, wt, dense_b, h, sums);
  k_gemm2<<<dim3(NN / 32), 256, 0, stream>>>(h, wt2, dec_b, sums, c_e, z);
  k_sim<<<dim3(64, 16), 256, 0, stream>>>(z, m_part, s_part, pos_arr);
  k_combine<<<dim3(NN / 256), 256, 0, stream>>>(m_part, s_part, pos_arr,
                                                row_loss);
  k_final<<<dim3(1), 256, 0, stream>>>(row_loss, out);
}

// Round 5
// 210.820 us; speedup vs baseline: 1.0141x; 1.0141x over previous
//
#include <hip/hip_runtime.h>
#include <math.h>
#include <stdint.h>

#define NN 8192
#define HID 1024
#define PROJ 128

constexpr float INV_T = 1.0f / 0.07f;
constexpr float LN_EPS = 1e-12f;
// exp((d-m)/T) = exp2((d-m)*CC)
constexpr float CC = 14.285714285714286f * 1.4426950408889634f;

typedef __bf16 bf16x8 __attribute__((ext_vector_type(8)));
typedef float f32x4 __attribute__((ext_vector_type(4)));

#define EXP2(x) __builtin_amdgcn_exp2f(x)

#define GLD16(g, l)                                                     \
  __builtin_amdgcn_global_load_lds(                                     \
      (const __attribute__((address_space(1))) uint32_t*)(g),           \
      (__attribute__((address_space(3))) uint32_t*)(l), 16, 0, 0)

__device__ __forceinline__ uint16_t f2bf(float f) {
  union { float f; uint32_t u; } c; c.f = f;
  uint32_t r = (c.u + 0x7FFFu + ((c.u >> 16) & 1u)) >> 16;
  return (uint16_t)r;
}
__device__ __forceinline__ float bf2f(uint16_t u) {
  union { uint32_t u; float f; } c; c.u = ((uint32_t)u) << 16;
  return c.f;
}

// gelu(v) ~= v * sigmoid(2u), u = 0.79788456(v + 0.044715 v^3)
__device__ __forceinline__ float gelu_f(float v) {
  float w = v * v;
  float u = v * fmaf(w, 0.0356774081f, 0.7978845608f);
  float e = EXP2(u * -2.8853900818f);
  return v * __builtin_amdgcn_rcpf(1.0f + e);
}

// ------------- convert fp32 -> bf16; also zero stats/c_e buffers ----------
__global__ __launch_bounds__(256) void k_conv(const float* __restrict__ in,
                                              uint16_t* __restrict__ out,
                                              float* __restrict__ sums,
                                              float* __restrict__ c_e) {
  const int b = blockIdx.x, t = threadIdx.x;
  if (b < 64) sums[b * 256 + t] = 0.f;       // sum[8192] + sumsq[8192]
  else if (b == 64) c_e[t] = 0.f;            // c[128] + e[128]
  int i = (b * 256 + t) * 4;
  float4 v = *(const float4*)(in + i);
  ushort4 o;
  o.x = f2bf(v.x); o.y = f2bf(v.y); o.z = f2bf(v.z); o.w = f2bf(v.w);
  *(ushort4*)(out + i) = o;
}

// ------------- transpose+convert: fp32 [R][C] -> bf16 [C][R] --------------
__global__ __launch_bounds__(256) void k_t1(const float* __restrict__ in,
                                            uint16_t* __restrict__ out,
                                            int R, int C) {
  __shared__ uint16_t t[32][33];
  const int cb = blockIdx.x * 32, rb = blockIdx.y * 32;
  const int tr = threadIdx.x >> 3, tc4 = (threadIdx.x & 7) * 4;
  float4 v = *(const float4*)(in + (size_t)(rb + tr) * C + cb + tc4);
  t[tc4 + 0][tr] = f2bf(v.x);
  t[tc4 + 1][tr] = f2bf(v.y);
  t[tc4 + 2][tr] = f2bf(v.z);
  t[tc4 + 3][tr] = f2bf(v.w);
  __syncthreads();
  const int oc = threadIdx.x >> 3, or4 = (threadIdx.x & 7) * 4;
  ushort4 o;
  o.x = t[oc][or4 + 0]; o.y = t[oc][or4 + 1];
  o.z = t[oc][or4 + 2]; o.w = t[oc][or4 + 3];
  *(ushort4*)(out + (size_t)(cb + oc) * R + rb + or4) = o;
}

// --- dec_w: transpose + fold gamma -> bf16 [128][1024]; column sums c,e ---
__global__ __launch_bounds__(256) void k_t2(const float* __restrict__ in,
                                            const float* __restrict__ gamma,
                                            const float* __restrict__ beta,
                                            uint16_t* __restrict__ out,
                                            float* __restrict__ c_e) {
  __shared__ float tg[32][33];
  __shared__ float tb[32][33];
  const int cb = blockIdx.x * 32, rb = blockIdx.y * 32;
  const int tr = threadIdx.x >> 3, tc4 = (threadIdx.x & 7) * 4;
  const float g = gamma[rb + tr], be = beta[rb + tr];
  float4 v = *(const float4*)(in + (size_t)(rb + tr) * PROJ + cb + tc4);
  tg[tc4 + 0][tr] = g * v.x;  tb[tc4 + 0][tr] = be * v.x;
  tg[tc4 + 1][tr] = g * v.y;  tb[tc4 + 1][tr] = be * v.y;
  tg[tc4 + 2][tr] = g * v.z;  tb[tc4 + 2][tr] = be * v.z;
  tg[tc4 + 3][tr] = g * v.w;  tb[tc4 + 3][tr] = be * v.w;
  __syncthreads();
  const int oc = threadIdx.x >> 3, or4 = (threadIdx.x & 7) * 4;
  ushort4 o;
  o.x = f2bf(tg[oc][or4 + 0]); o.y = f2bf(tg[oc][or4 + 1]);
  o.z = f2bf(tg[oc][or4 + 2]); o.w = f2bf(tg[oc][or4 + 3]);
  *(ushort4*)(out + (size_t)(cb + oc) * HID + rb + or4) = o;
  if (threadIdx.x < 32) {
    float sc = 0.f, se = 0.f;
#pragma unroll
    for (int d = 0; d < 32; ++d) { sc += tg[threadIdx.x][d]; se += tb[threadIdx.x][d]; }
    atomicAdd(c_e + cb + threadIdx.x, sc);
    atomicAdd(c_e + 128 + cb + threadIdx.x, se);
  }
}

// -------- GEMM1: h = gelu(x@W+b) bf16, + per-row sum/sumsq atomics --------
// 64x128 tile, BK=64 (two 32-k LDS panels, GLD16-compatible), grid (8,128).
__global__ __launch_bounds__(256) void k_gemm1(
    const uint16_t* __restrict__ Ab, const uint16_t* __restrict__ Bt,
    const float* __restrict__ bias, uint16_t* __restrict__ Hout,
    float* __restrict__ sums) {
  __shared__ __align__(16) uint16_t As[2 * 64 * 32];
  __shared__ __align__(16) uint16_t Bs[2 * 128 * 32];
  const int tid = threadIdx.x;
  const int bn = blockIdx.x * 128, bm = blockIdx.y * 64;
  const int wave = tid >> 6, lane = tid & 63;
  const int wx = wave & 1, wy = wave >> 1;
  const int col = lane & 15, quad = lane >> 4;
  f32x4 acc[2][4] = {};
  const char* Abase = (const char*)Ab;
  const char* Bbase = (const char*)Bt;
  for (int k0 = 0; k0 < HID; k0 += 64) {
    __syncthreads();
#pragma unroll
    for (int l = 0; l < 2; ++l) {
      int off = tid * 16 + l * 4096;
      int h = off >> 12, row = (off >> 6) & 63, inner = off & 63;
      GLD16(Abase + ((size_t)(bm + row) * HID + k0 + h * 32) * 2 + inner,
            (char*)As + off);
    }
#pragma unroll
    for (int l = 0; l < 4; ++l) {
      int off = tid * 16 + l * 4096;
      int h = off >> 13, row = (off >> 6) & 127, inner = off & 63;
      GLD16(Bbase + ((size_t)(bn + row) * HID + k0 + h * 32) * 2 + inner,
            (char*)Bs + off);
    }
    __syncthreads();
#pragma unroll
    for (int h = 0; h < 2; ++h) {
      bf16x8 a[2], b[4];
#pragma unroll
      for (int mt = 0; mt < 2; ++mt)
        a[mt] = *(const bf16x8*)&As[h * 2048 +
                                    (wy * 32 + mt * 16 + col) * 32 + quad * 8];
#pragma unroll
      for (int nt = 0; nt < 4; ++nt)
        b[nt] = *(const bf16x8*)&Bs[h * 4096 +
                                    (wx * 64 + nt * 16 + col) * 32 + quad * 8];
#pragma unroll
      for (int mt = 0; mt < 2; ++mt)
#pragma unroll
        for (int nt = 0; nt < 4; ++nt)
          acc[mt][nt] = __builtin_amdgcn_mfma_f32_16x16x32_bf16(
              a[mt], b[nt], acc[mt][nt], 0, 0, 0);
    }
  }
  float rsum[2][4] = {}, rsq[2][4] = {};
#pragma unroll
  for (int nt = 0; nt < 4; ++nt) {
    int gj = bn + wx * 64 + nt * 16 + col;
    float bv = bias[gj];
#pragma unroll
    for (int mt = 0; mt < 2; ++mt)
#pragma unroll
      for (int r = 0; r < 4; ++r) {
        int gi = bm + wy * 32 + mt * 16 + quad * 4 + r;
        float gl = gelu_f(acc[mt][nt][r] + bv);
        Hout[(size_t)gi * HID + gj] = f2bf(gl);
        rsum[mt][r] += gl;
        rsq[mt][r] = fmaf(gl, gl, rsq[mt][r]);
      }
  }
#pragma unroll
  for (int mt = 0; mt < 2; ++mt)
#pragma unroll
    for (int r = 0; r < 4; ++r) {
      float s1 = rsum[mt][r], s2 = rsq[mt][r];
#pragma unroll
      for (int off = 1; off < 16; off <<= 1) {
        s1 += __shfl_xor(s1, off, 64);
        s2 += __shfl_xor(s2, off, 64);
      }
      if (col == 0) {
        int gi = bm + wy * 32 + mt * 16 + quad * 4 + r;
        atomicAdd(&sums[gi], s1);
        atomicAdd(&sums[NN + gi], s2);
      }
    }
}

// --- GEMM2 with LN folded: z = r*(h@Wg) - r*mu*c + e + dec_b, bf16 out ----
__global__ __launch_bounds__(256) void k_gemm2(
    const uint16_t* __restrict__ Hb, const uint16_t* __restrict__ Wt2,
    const float* __restrict__ bd, const float* __restrict__ sums,
    const float* __restrict__ c_e, uint16_t* __restrict__ Z) {
  __shared__ __align__(16) uint16_t As2[32 * 32];
  __shared__ __align__(16) uint16_t Bs2[128 * 32];
  __shared__ float muS[32], rS[32];
  const int tid = threadIdx.x;
  const int bm = blockIdx.x * 32;
  const int wave = tid >> 6, lane = tid & 63;
  const int wx = wave & 1, wy = wave >> 1;
  const int col = lane & 15, quad = lane >> 4;
  if (tid < 32) {
    float s = sums[bm + tid], q = sums[NN + bm + tid];
    float mu = s * (1.0f / HID);
    float var = q * (1.0f / HID) - mu * mu;
    muS[tid] = mu;
    rS[tid] = rsqrtf(var + LN_EPS);
  }
  f32x4 acc[4] = {};
  const char* Abase = (const char*)Hb;
  const char* Bbase = (const char*)Wt2;
  for (int k0 = 0; k0 < HID; k0 += 32) {
    __syncthreads();
    if (tid < 128) {
      int off = tid * 16;
      int row = off >> 6, inner = off & 63;
      GLD16(Abase + ((size_t)(bm + row) * HID + k0) * 2 + inner,
            (char*)As2 + off);
    }
#pragma unroll
    for (int l = 0; l < 2; ++l) {
      int off = tid * 16 + l * 4096;
      int row = off >> 6, inner = off & 63;
      GLD16(Bbase + ((size_t)row * HID + k0) * 2 + inner, (char*)Bs2 + off);
    }
    __syncthreads();
    bf16x8 a = *(const bf16x8*)&As2[(wy * 16 + col) * 32 + quad * 8];
#pragma unroll
    for (int nt = 0; nt < 4; ++nt) {
      bf16x8 b = *(const bf16x8*)&Bs2[(wx * 64 + nt * 16 + col) * 32 + quad * 8];
      acc[nt] = __builtin_amdgcn_mfma_f32_16x16x32_bf16(a, b, acc[nt], 0, 0, 0);
    }
  }
#pragma unroll
  for (int nt = 0; nt < 4; ++nt) {
    int gj = wx * 64 + nt * 16 + col;
    float ck = c_e[gj], ek = c_e[128 + gj] + bd[gj];
#pragma unroll
    for (int r = 0; r < 4; ++r) {
      int li = wy * 16 + quad * 4 + r;
      float mu = muS[li], rr = rS[li];
      float z = fmaf(rr, acc[nt][r], fmaf(-rr * mu, ck, ek));
      Z[(size_t)(bm + li) * PROJ + gj] = f2bf(z);
    }
  }
}

// ------ flash logsumexp over Z Z^T: LDS-free + software-pipelined b -------
// grid (64, 16): block = 4 indep waves x 32 i-rows; chunk = 512 j.
// b-fragments double-buffered in registers: loads for stage n+1 issue
// before the MFMAs of stage n, so vmcnt waits overlap matrix work.
__device__ __forceinline__ void lse4(float& m, float& s, float v0, float v1,
                                     float v2, float v3) {
  float lm = fmaxf(fmaxf(v0, v1), fmaxf(v2, v3));
  float mn = fmaxf(m, lm);
  float tn = mn * CC;
  float rs = EXP2(fmaf(m, CC, -tn));
  float e = EXP2(fmaf(v0, CC, -tn)) + EXP2(fmaf(v1, CC, -tn)) +
            EXP2(fmaf(v2, CC, -tn)) + EXP2(fmaf(v3, CC, -tn));
  s = fmaf(s, rs, e);
  m = mn;
}

__global__ __launch_bounds__(256) void k_sim(const uint16_t* __restrict__ Z,
                                             float* __restrict__ m_part,
                                             float* __restrict__ s_part,
                                             float* __restrict__ pos_arr) {
  const int tid = threadIdx.x;
  const int wave = tid >> 6, lane = tid & 63;
  const int col = lane & 15, quad = lane >> 4;
  const int wrow0 = blockIdx.x * 128 + wave * 32;
  const int chunk = blockIdx.y;
  bf16x8 afr[2][4];
#pragma unroll
  for (int mt = 0; mt < 2; ++mt)
#pragma unroll
    for (int kc = 0; kc < 4; ++kc)
      afr[mt][kc] = *(const bf16x8*)(Z +
          (size_t)(wrow0 + mt * 16 + col) * PROJ + kc * 32 + quad * 8);
  float ms[8], ss[8];
#pragma unroll
  for (int i = 0; i < 8; ++i) { ms[i] = -INFINITY; ss[i] = 0.f; }
  const int diag_t = wrow0 & ~63;
  const int pos_t = ((wrow0 + NN / 2) & (NN - 1)) & ~63;
  const int jbase = chunk * 512;

  bf16x8 b0[4], b1[4];
#define LOADB(dst, jtv, kcv)                                                \
  _Pragma("unroll") for (int nt = 0; nt < 4; ++nt)                          \
      dst[nt] = *(const bf16x8*)(Z + (size_t)((jtv) + nt * 16 + col) * PROJ + \
                                 (kcv) * 32 + quad * 8);
#define MFMA8(bb, kcv)                                                      \
  _Pragma("unroll") for (int mt = 0; mt < 2; ++mt)                          \
      _Pragma("unroll") for (int nt = 0; nt < 4; ++nt)                      \
          acc[mt][nt] = __builtin_amdgcn_mfma_f32_16x16x32_bf16(            \
              afr[mt][kcv], bb[nt], acc[mt][nt], 0, 0, 0);

  LOADB(b0, jbase, 0);
  for (int t8 = 0; t8 < 8; ++t8) {
    const int jt = jbase + t8 * 64;
    const int jn = jbase + ((t8 + 1) & 7) * 64;  // wraps at end (harmless)
    f32x4 acc[2][4] = {};
    LOADB(b1, jt, 1);
    MFMA8(b0, 0);
    LOADB(b0, jt, 2);
    MFMA8(b1, 1);
    LOADB(b1, jt, 3);
    MFMA8(b0, 2);
    LOADB(b0, jn, 0);
    MFMA8(b1, 3);
    if (jt != diag_t && jt != pos_t) {
#pragma unroll
      for (int mt = 0; mt < 2; ++mt)
#pragma unroll
        for (int r = 0; r < 4; ++r)
          lse4(ms[mt * 4 + r], ss[mt * 4 + r], acc[mt][0][r], acc[mt][1][r],
               acc[mt][2][r], acc[mt][3][r]);
    } else {
      const bool isd = (jt == diag_t);
#pragma unroll
      for (int mt = 0; mt < 2; ++mt)
#pragma unroll
        for (int r = 0; r < 4; ++r) {
          int gi = wrow0 + mt * 16 + quad * 4 + r;
          int partner = (gi + NN / 2) & (NN - 1);
          float v[4];
#pragma unroll
          for (int nt = 0; nt < 4; ++nt) {
            int gj = jt + nt * 16 + col;
            float d = acc[mt][nt][r];
            if (!isd && gj == partner) pos_arr[gi] = d;
            v[nt] = (isd && gj == gi) ? -INFINITY : d;
          }
          lse4(ms[mt * 4 + r], ss[mt * 4 + r], v[0], v[1], v[2], v[3]);
        }
    }
  }
#undef LOADB
#undef MFMA8
#pragma unroll
  for (int ri = 0; ri < 8; ++ri) {
#pragma unroll
    for (int off = 1; off < 16; off <<= 1) {
      float om = __shfl_xor(ms[ri], off, 64);
      float os = __shfl_xor(ss[ri], off, 64);
      float mn = fmaxf(ms[ri], om);
      float tn = mn * CC;
      ss[ri] = fmaf(ss[ri], EXP2(fmaf(ms[ri], CC, -tn)),
                    os * EXP2(fmaf(om, CC, -tn)));
      ms[ri] = mn;
    }
  }
  if (col == 0) {
#pragma unroll
    for (int ri = 0; ri < 8; ++ri) {
      int gi = wrow0 + (ri >> 2) * 16 + quad * 4 + (ri & 3);
      m_part[(size_t)chunk * NN + gi] = ms[ri];
      s_part[(size_t)chunk * NN + gi] = ss[ri];
    }
  }
}

// ---------------- combine 16 chunk-partials per row ----------------
__global__ __launch_bounds__(256) void k_combine(
    const float* __restrict__ m_part, const float* __restrict__ s_part,
    const float* __restrict__ pos_arr, float* __restrict__ row_loss) {
  const int i = blockIdx.x * 256 + threadIdx.x;
  float M = -INFINITY;
#pragma unroll
  for (int p = 0; p < 16; ++p) M = fmaxf(M, m_part[(size_t)p * NN + i]);
  float S = 0.f;
  float t = M * CC;
#pragma unroll
  for (int p = 0; p < 16; ++p)
    S += s_part[(size_t)p * NN + i] * EXP2(fmaf(m_part[(size_t)p * NN + i], CC, -t));
  row_loss[i] = (M - pos_arr[i]) * INV_T + logf(S);
}

// ---------------- mean over rows ----------------
__global__ __launch_bounds__(256) void k_final(
    const float* __restrict__ row_loss, float* __restrict__ out) {
  const int tid = threadIdx.x;
  float s = 0.f;
#pragma unroll
  for (int l = 0; l < 32; ++l) s += row_loss[tid + l * 256];
#pragma unroll
  for (int off = 32; off > 0; off >>= 1) s += __shfl_down(s, off);
  __shared__ float red[4];
  const int wave = tid >> 6, lane = tid & 63;
  if (lane == 0) red[wave] = s;
  __syncthreads();
  if (tid == 0) out[0] = (red[0] + red[1] + red[2] + red[3]) * (1.0f / NN);
}

extern "C" void kernel_launch(void* const* d_in, const int* in_sizes, int n_in,
                              void* d_out, int out_size, void* d_ws,
                              size_t ws_size, hipStream_t stream) {
  const float* x       = (const float*)d_in[0];
  const float* dense_w = (const float*)d_in[1];
  const float* dense_b = (const float*)d_in[2];
  const float* ln_g    = (const float*)d_in[3];
  const float* ln_b    = (const float*)d_in[4];
  const float* dec_w   = (const float*)d_in[5];
  const float* dec_b   = (const float*)d_in[6];
  float* out = (float*)d_out;
  char* ws = (char*)d_ws;
  // Phase 1 (through gemm1): xb [0,16M), wt [16M,18M), h [18M,34M)
  // Phase 2 (after gemm1):   z  [0,2M),  m_part/s_part reuse wt region
  uint16_t* xb      = (uint16_t*)(ws);
  uint16_t* wt      = (uint16_t*)(ws + 16777216);
  uint16_t* h       = (uint16_t*)(ws + 18874368);
  uint16_t* z       = (uint16_t*)(ws);
  float*    m_part  = (float*)(ws + 16777216);     // 16*8192*4 = 512 KiB
  float*    s_part  = (float*)(ws + 17301504);     // 512 KiB
  uint16_t* wt2     = (uint16_t*)(ws + 35651584);  // 256 KiB [128][1024]
  float*    sums    = (float*)(ws + 35913728);     // 64 KiB: sum|sumsq
  float*    c_e     = (float*)(ws + 35979264);     // 1 KiB: c[128]|e[128]
  float*    pos_arr = (float*)(ws + 35980288);     // 32 KiB
  float*    row_loss= (float*)(ws + 36013056);     // 32 KiB

  k_conv<<<dim3(NN * HID / 1024), 256, 0, stream>>>(x, xb, sums, c_e);
  k_t1<<<dim3(32, 32), 256, 0, stream>>>(dense_w, wt, HID, HID);
  k_t2<<<dim3(PROJ / 32, HID / 32), 256, 0, stream>>>(dec_w, ln_g, ln_b, wt2,
                                                      c_e);
  k_gemm1<<<dim3(8, 128), 256, 0, stream>>>(xb, wt, dense_b, h, sums);
  k_gemm2<<<dim3(NN / 32), 256, 0, stream>>>(h, wt2, dec_b, sums, c_e, z);
  k_sim<<<dim3(64, 16), 256, 0, stream>>>(z, m_part, s_part, pos_arr);
  k_combine<<<dim3(NN / 256), 256, 0, stream>>>(m_part, s_part, pos_arr,
                                                row_loss);
  k_final<<<dim3(1), 256, 0, stream>>>(row_loss, out);
}

// Round 6
// 200.648 us; speedup vs baseline: 1.0655x; 1.0507x over previous
//
#include <hip/hip_runtime.h>
#include <math.h>
#include <stdint.h>

#define NN 8192
#define HID 1024
#define PROJ 128

constexpr float INV_T = 1.0f / 0.07f;
constexpr float LN_EPS = 1e-12f;
// exp((d-m)/T) = exp2((d-m)*CC)
constexpr float CC = 14.285714285714286f * 1.4426950408889634f;

typedef __bf16 bf16x8 __attribute__((ext_vector_type(8)));
typedef float f32x4 __attribute__((ext_vector_type(4)));

#define EXP2(x) __builtin_amdgcn_exp2f(x)

#define GLD16(g, l)                                                     \
  __builtin_amdgcn_global_load_lds(                                     \
      (const __attribute__((address_space(1))) uint32_t*)(g),           \
      (__attribute__((address_space(3))) uint32_t*)(l), 16, 0, 0)

__device__ __forceinline__ uint16_t f2bf(float f) {
  union { float f; uint32_t u; } c; c.f = f;
  uint32_t r = (c.u + 0x7FFFu + ((c.u >> 16) & 1u)) >> 16;
  return (uint16_t)r;
}
__device__ __forceinline__ float bf2f(uint16_t u) {
  union { uint32_t u; float f; } c; c.u = ((uint32_t)u) << 16;
  return c.f;
}

// gelu(v) ~= v * sigmoid(2u), u = 0.79788456(v + 0.044715 v^3)
__device__ __forceinline__ float gelu_f(float v) {
  float w = v * v;
  float u = v * fmaf(w, 0.0356774081f, 0.7978845608f);
  float e = EXP2(u * -2.8853900818f);
  return v * __builtin_amdgcn_rcpf(1.0f + e);
}

// ------------- convert fp32 -> bf16; also zero stats/c_e buffers ----------
__global__ __launch_bounds__(256) void k_conv(const float* __restrict__ in,
                                              uint16_t* __restrict__ out,
                                              float* __restrict__ sums,
                                              float* __restrict__ c_e) {
  const int b = blockIdx.x, t = threadIdx.x;
  if (b < 64) sums[b * 256 + t] = 0.f;       // sum[8192] + sumsq[8192]
  else if (b == 64) c_e[t] = 0.f;            // c[128] + e[128]
  int i = (b * 256 + t) * 4;
  float4 v = *(const float4*)(in + i);
  ushort4 o;
  o.x = f2bf(v.x); o.y = f2bf(v.y); o.z = f2bf(v.z); o.w = f2bf(v.w);
  *(ushort4*)(out + i) = o;
}

// ------------- transpose+convert: fp32 [R][C] -> bf16 [C][R] --------------
__global__ __launch_bounds__(256) void k_t1(const float* __restrict__ in,
                                            uint16_t* __restrict__ out,
                                            int R, int C) {
  __shared__ uint16_t t[32][33];
  const int cb = blockIdx.x * 32, rb = blockIdx.y * 32;
  const int tr = threadIdx.x >> 3, tc4 = (threadIdx.x & 7) * 4;
  float4 v = *(const float4*)(in + (size_t)(rb + tr) * C + cb + tc4);
  t[tc4 + 0][tr] = f2bf(v.x);
  t[tc4 + 1][tr] = f2bf(v.y);
  t[tc4 + 2][tr] = f2bf(v.z);
  t[tc4 + 3][tr] = f2bf(v.w);
  __syncthreads();
  const int oc = threadIdx.x >> 3, or4 = (threadIdx.x & 7) * 4;
  ushort4 o;
  o.x = t[oc][or4 + 0]; o.y = t[oc][or4 + 1];
  o.z = t[oc][or4 + 2]; o.w = t[oc][or4 + 3];
  *(ushort4*)(out + (size_t)(cb + oc) * R + rb + or4) = o;
}

// --- dec_w: transpose + fold gamma -> bf16 [128][1024]; column sums c,e ---
__global__ __launch_bounds__(256) void k_t2(const float* __restrict__ in,
                                            const float* __restrict__ gamma,
                                            const float* __restrict__ beta,
                                            uint16_t* __restrict__ out,
                                            float* __restrict__ c_e) {
  __shared__ float tg[32][33];
  __shared__ float tb[32][33];
  const int cb = blockIdx.x * 32, rb = blockIdx.y * 32;
  const int tr = threadIdx.x >> 3, tc4 = (threadIdx.x & 7) * 4;
  const float g = gamma[rb + tr], be = beta[rb + tr];
  float4 v = *(const float4*)(in + (size_t)(rb + tr) * PROJ + cb + tc4);
  tg[tc4 + 0][tr] = g * v.x;  tb[tc4 + 0][tr] = be * v.x;
  tg[tc4 + 1][tr] = g * v.y;  tb[tc4 + 1][tr] = be * v.y;
  tg[tc4 + 2][tr] = g * v.z;  tb[tc4 + 2][tr] = be * v.z;
  tg[tc4 + 3][tr] = g * v.w;  tb[tc4 + 3][tr] = be * v.w;
  __syncthreads();
  const int oc = threadIdx.x >> 3, or4 = (threadIdx.x & 7) * 4;
  ushort4 o;
  o.x = f2bf(tg[oc][or4 + 0]); o.y = f2bf(tg[oc][or4 + 1]);
  o.z = f2bf(tg[oc][or4 + 2]); o.w = f2bf(tg[oc][or4 + 3]);
  *(ushort4*)(out + (size_t)(cb + oc) * HID + rb + or4) = o;
  if (threadIdx.x < 32) {
    float sc = 0.f, se = 0.f;
#pragma unroll
    for (int d = 0; d < 32; ++d) { sc += tg[threadIdx.x][d]; se += tb[threadIdx.x][d]; }
    atomicAdd(c_e + cb + threadIdx.x, sc);
    atomicAdd(c_e + 128 + cb + threadIdx.x, se);
  }
}

// -------- GEMM1: h = gelu(x@W+b) bf16, + per-row sum/sumsq atomics --------
// 64x128 tile, BK=64 (two 32-k LDS panels, GLD16-compatible), grid (8,128).
__global__ __launch_bounds__(256) void k_gemm1(
    const uint16_t* __restrict__ Ab, const uint16_t* __restrict__ Bt,
    const float* __restrict__ bias, uint16_t* __restrict__ Hout,
    float* __restrict__ sums) {
  __shared__ __align__(16) uint16_t As[2 * 64 * 32];
  __shared__ __align__(16) uint16_t Bs[2 * 128 * 32];
  const int tid = threadIdx.x;
  const int bn = blockIdx.x * 128, bm = blockIdx.y * 64;
  const int wave = tid >> 6, lane = tid & 63;
  const int wx = wave & 1, wy = wave >> 1;
  const int col = lane & 15, quad = lane >> 4;
  f32x4 acc[2][4] = {};
  const char* Abase = (const char*)Ab;
  const char* Bbase = (const char*)Bt;
  for (int k0 = 0; k0 < HID; k0 += 64) {
    __syncthreads();
#pragma unroll
    for (int l = 0; l < 2; ++l) {
      int off = tid * 16 + l * 4096;
      int h = off >> 12, row = (off >> 6) & 63, inner = off & 63;
      GLD16(Abase + ((size_t)(bm + row) * HID + k0 + h * 32) * 2 + inner,
            (char*)As + off);
    }
#pragma unroll
    for (int l = 0; l < 4; ++l) {
      int off = tid * 16 + l * 4096;
      int h = off >> 13, row = (off >> 6) & 127, inner = off & 63;
      GLD16(Bbase + ((size_t)(bn + row) * HID + k0 + h * 32) * 2 + inner,
            (char*)Bs + off);
    }
    __syncthreads();
#pragma unroll
    for (int h = 0; h < 2; ++h) {
      bf16x8 a[2], b[4];
#pragma unroll
      for (int mt = 0; mt < 2; ++mt)
        a[mt] = *(const bf16x8*)&As[h * 2048 +
                                    (wy * 32 + mt * 16 + col) * 32 + quad * 8];
#pragma unroll
      for (int nt = 0; nt < 4; ++nt)
        b[nt] = *(const bf16x8*)&Bs[h * 4096 +
                                    (wx * 64 + nt * 16 + col) * 32 + quad * 8];
#pragma unroll
      for (int mt = 0; mt < 2; ++mt)
#pragma unroll
        for (int nt = 0; nt < 4; ++nt)
          acc[mt][nt] = __builtin_amdgcn_mfma_f32_16x16x32_bf16(
              a[mt], b[nt], acc[mt][nt], 0, 0, 0);
    }
  }
  float rsum[2][4] = {}, rsq[2][4] = {};
#pragma unroll
  for (int nt = 0; nt < 4; ++nt) {
    int gj = bn + wx * 64 + nt * 16 + col;
    float bv = bias[gj];
#pragma unroll
    for (int mt = 0; mt < 2; ++mt)
#pragma unroll
      for (int r = 0; r < 4; ++r) {
        int gi = bm + wy * 32 + mt * 16 + quad * 4 + r;
        float gl = gelu_f(acc[mt][nt][r] + bv);
        Hout[(size_t)gi * HID + gj] = f2bf(gl);
        rsum[mt][r] += gl;
        rsq[mt][r] = fmaf(gl, gl, rsq[mt][r]);
      }
  }
#pragma unroll
  for (int mt = 0; mt < 2; ++mt)
#pragma unroll
    for (int r = 0; r < 4; ++r) {
      float s1 = rsum[mt][r], s2 = rsq[mt][r];
#pragma unroll
      for (int off = 1; off < 16; off <<= 1) {
        s1 += __shfl_xor(s1, off, 64);
        s2 += __shfl_xor(s2, off, 64);
      }
      if (col == 0) {
        int gi = bm + wy * 32 + mt * 16 + quad * 4 + r;
        atomicAdd(&sums[gi], s1);
        atomicAdd(&sums[NN + gi], s2);
      }
    }
}

// --- GEMM2 with LN folded: z = r*(h@Wg) - r*mu*c + e + dec_b, bf16 out ----
__global__ __launch_bounds__(256) void k_gemm2(
    const uint16_t* __restrict__ Hb, const uint16_t* __restrict__ Wt2,
    const float* __restrict__ bd, const float* __restrict__ sums,
    const float* __restrict__ c_e, uint16_t* __restrict__ Z) {
  __shared__ __align__(16) uint16_t As2[32 * 32];
  __shared__ __align__(16) uint16_t Bs2[128 * 32];
  __shared__ float muS[32], rS[32];
  const int tid = threadIdx.x;
  const int bm = blockIdx.x * 32;
  const int wave = tid >> 6, lane = tid & 63;
  const int wx = wave & 1, wy = wave >> 1;
  const int col = lane & 15, quad = lane >> 4;
  if (tid < 32) {
    float s = sums[bm + tid], q = sums[NN + bm + tid];
    float mu = s * (1.0f / HID);
    float var = q * (1.0f / HID) - mu * mu;
    muS[tid] = mu;
    rS[tid] = rsqrtf(var + LN_EPS);
  }
  f32x4 acc[4] = {};
  const char* Abase = (const char*)Hb;
  const char* Bbase = (const char*)Wt2;
  for (int k0 = 0; k0 < HID; k0 += 32) {
    __syncthreads();
    if (tid < 128) {
      int off = tid * 16;
      int row = off >> 6, inner = off & 63;
      GLD16(Abase + ((size_t)(bm + row) * HID + k0) * 2 + inner,
            (char*)As2 + off);
    }
#pragma unroll
    for (int l = 0; l < 2; ++l) {
      int off = tid * 16 + l * 4096;
      int row = off >> 6, inner = off & 63;
      GLD16(Bbase + ((size_t)row * HID + k0) * 2 + inner, (char*)Bs2 + off);
    }
    __syncthreads();
    bf16x8 a = *(const bf16x8*)&As2[(wy * 16 + col) * 32 + quad * 8];
#pragma unroll
    for (int nt = 0; nt < 4; ++nt) {
      bf16x8 b = *(const bf16x8*)&Bs2[(wx * 64 + nt * 16 + col) * 32 + quad * 8];
      acc[nt] = __builtin_amdgcn_mfma_f32_16x16x32_bf16(a, b, acc[nt], 0, 0, 0);
    }
  }
#pragma unroll
  for (int nt = 0; nt < 4; ++nt) {
    int gj = wx * 64 + nt * 16 + col;
    float ck = c_e[gj], ek = c_e[128 + gj] + bd[gj];
#pragma unroll
    for (int r = 0; r < 4; ++r) {
      int li = wy * 16 + quad * 4 + r;
      float mu = muS[li], rr = rS[li];
      float z = fmaf(rr, acc[nt][r], fmaf(-rr * mu, ck, ek));
      Z[(size_t)(bm + li) * PROJ + gj] = f2bf(z);
    }
  }
}

// ------ flash logsumexp over Z Z^T: block-shared LDS j-tiles --------------
// Block = 4 waves x 64 i-rows = 256 i. j staged 64x128 (16 KB) in LDS,
// XOR-swizzled so GLD16's lane-linear layout still gives conflict-free
// ds_read_b128 fragment reads. Single barrier per tile (stage t+1 issued
// before compute t). grid (32, 16): chunk = 512 j.
__device__ __forceinline__ void lse4(float& m, float& s, float v0, float v1,
                                     float v2, float v3) {
  float lm = fmaxf(fmaxf(v0, v1), fmaxf(v2, v3));
  float mn = fmaxf(m, lm);
  float tn = mn * CC;
  float rs = EXP2(fmaf(m, CC, -tn));
  float e = EXP2(fmaf(v0, CC, -tn)) + EXP2(fmaf(v1, CC, -tn)) +
            EXP2(fmaf(v2, CC, -tn)) + EXP2(fmaf(v3, CC, -tn));
  s = fmaf(s, rs, e);
  m = mn;
}

__global__ __launch_bounds__(256, 2) void k_sim(const uint16_t* __restrict__ Z,
                                                float* __restrict__ m_part,
                                                float* __restrict__ s_part,
                                                float* __restrict__ pos_arr) {
  __shared__ __align__(16) uint16_t Bsh[2][64 * 128];
  const int tid = threadIdx.x;
  const int wave = tid >> 6, lane = tid & 63;
  const int col = lane & 15, quad = lane >> 4;
  const int wrow0 = blockIdx.x * 256 + wave * 64;
  const int chunk = blockIdx.y;
  const char* Zb = (const char*)Z;

  // A fragments: 64 i-rows per wave, K=128, in registers (64 VGPRs)
  bf16x8 afr[4][4];
#pragma unroll
  for (int mt = 0; mt < 4; ++mt)
#pragma unroll
    for (int kc = 0; kc < 4; ++kc)
      afr[mt][kc] = *(const bf16x8*)(Z +
          (size_t)(wrow0 + mt * 16 + col) * PROJ + kc * 32 + quad * 8);

  float ms[16], ss[16];
#pragma unroll
  for (int i = 0; i < 16; ++i) { ms[i] = -INFINITY; ss[i] = 0.f; }

  const int diag_t = wrow0;                        // 64-aligned
  const int pos_t = (wrow0 + NN / 2) & (NN - 1);   // 64-aligned
  const int jbase = chunk * 512;

  // stage tile t into buffer buf; source chunk XOR-swizzled by row&7
#define STAGE(t, bufv)                                                      \
  {                                                                         \
    const int j0s = jbase + (t) * 64;                                       \
    _Pragma("unroll") for (int l = 0; l < 4; ++l) {                         \
      int off = tid * 16 + l * 4096;                                        \
      int row = off >> 8;                                                   \
      int p = (off >> 4) & 15;                                              \
      GLD16(Zb + (size_t)(j0s + row) * 256 + ((p ^ (row & 7)) << 4),        \
            (char*)&Bsh[bufv][0] + off);                                    \
    }                                                                       \
  }

  STAGE(0, 0);
  for (int t = 0; t < 8; ++t) {
    const int buf = t & 1;
    __syncthreads();   // staging of tile t landed; all waves done with buf
    if (t < 7) STAGE(t + 1, buf ^ 1);
    const int jt = jbase + t * 64;
    f32x4 acc[4][4] = {};
#pragma unroll
    for (int kc = 0; kc < 4; ++kc) {
      bf16x8 b[4];
#pragma unroll
      for (int nt = 0; nt < 4; ++nt) {
        int r = nt * 16 + col;
        b[nt] = *(const bf16x8*)&Bsh[buf][r * 128 +
                                         (((kc * 4 + quad) ^ (col & 7)) << 3)];
      }
#pragma unroll
      for (int mt = 0; mt < 4; ++mt)
#pragma unroll
        for (int nt = 0; nt < 4; ++nt)
          acc[mt][nt] = __builtin_amdgcn_mfma_f32_16x16x32_bf16(
              afr[mt][kc], b[nt], acc[mt][nt], 0, 0, 0);
    }
    if (jt != diag_t && jt != pos_t) {
#pragma unroll
      for (int mt = 0; mt < 4; ++mt)
#pragma unroll
        for (int r = 0; r < 4; ++r)
          lse4(ms[mt * 4 + r], ss[mt * 4 + r], acc[mt][0][r], acc[mt][1][r],
               acc[mt][2][r], acc[mt][3][r]);
    } else {
      const bool isd = (jt == diag_t);
#pragma unroll
      for (int mt = 0; mt < 4; ++mt)
#pragma unroll
        for (int r = 0; r < 4; ++r) {
          int gi = wrow0 + mt * 16 + quad * 4 + r;
          int partner = (gi + NN / 2) & (NN - 1);
          float v[4];
#pragma unroll
          for (int nt = 0; nt < 4; ++nt) {
            int gj = jt + nt * 16 + col;
            float d = acc[mt][nt][r];
            if (!isd && gj == partner) pos_arr[gi] = d;
            v[nt] = (isd && gj == gi) ? -INFINITY : d;
          }
          lse4(ms[mt * 4 + r], ss[mt * 4 + r], v[0], v[1], v[2], v[3]);
        }
    }
  }
#undef STAGE
  // reduce (m,s) across the 16 col-lanes sharing the same rows
#pragma unroll
  for (int ri = 0; ri < 16; ++ri) {
#pragma unroll
    for (int off = 1; off < 16; off <<= 1) {
      float om = __shfl_xor(ms[ri], off, 64);
      float os = __shfl_xor(ss[ri], off, 64);
      float mn = fmaxf(ms[ri], om);
      float tn = mn * CC;
      ss[ri] = fmaf(ss[ri], EXP2(fmaf(ms[ri], CC, -tn)),
                    os * EXP2(fmaf(om, CC, -tn)));
      ms[ri] = mn;
    }
  }
  if (col == 0) {
#pragma unroll
    for (int ri = 0; ri < 16; ++ri) {
      int gi = wrow0 + (ri >> 2) * 16 + quad * 4 + (ri & 3);
      m_part[(size_t)chunk * NN + gi] = ms[ri];
      s_part[(size_t)chunk * NN + gi] = ss[ri];
    }
  }
}

// ---------------- combine 16 chunk-partials per row ----------------
__global__ __launch_bounds__(256) void k_combine(
    const float* __restrict__ m_part, const float* __restrict__ s_part,
    const float* __restrict__ pos_arr, float* __restrict__ row_loss) {
  const int i = blockIdx.x * 256 + threadIdx.x;
  float M = -INFINITY;
#pragma unroll
  for (int p = 0; p < 16; ++p) M = fmaxf(M, m_part[(size_t)p * NN + i]);
  float S = 0.f;
  float t = M * CC;
#pragma unroll
  for (int p = 0; p < 16; ++p)
    S += s_part[(size_t)p * NN + i] * EXP2(fmaf(m_part[(size_t)p * NN + i], CC, -t));
  row_loss[i] = (M - pos_arr[i]) * INV_T + logf(S);
}

// ---------------- mean over rows ----------------
__global__ __launch_bounds__(256) void k_final(
    const float* __restrict__ row_loss, float* __restrict__ out) {
  const int tid = threadIdx.x;
  float s = 0.f;
#pragma unroll
  for (int l = 0; l < 32; ++l) s += row_loss[tid + l * 256];
#pragma unroll
  for (int off = 32; off > 0; off >>= 1) s += __shfl_down(s, off);
  __shared__ float red[4];
  const int wave = tid >> 6, lane = tid & 63;
  if (lane == 0) red[wave] = s;
  __syncthreads();
  if (tid == 0) out[0] = (red[0] + red[1] + red[2] + red[3]) * (1.0f / NN);
}

extern "C" void kernel_launch(void* const* d_in, const int* in_sizes, int n_in,
                              void* d_out, int out_size, void* d_ws,
                              size_t ws_size, hipStream_t stream) {
  const float* x       = (const float*)d_in[0];
  const float* dense_w = (const float*)d_in[1];
  const float* dense_b = (const float*)d_in[2];
  const float* ln_g    = (const float*)d_in[3];
  const float* ln_b    = (const float*)d_in[4];
  const float* dec_w   = (const float*)d_in[5];
  const float* dec_b   = (const float*)d_in[6];
  float* out = (float*)d_out;
  char* ws = (char*)d_ws;
  // Phase 1 (through gemm1): xb [0,16M), wt [16M,18M), h [18M,34M)
  // Phase 2 (after gemm1):   z  [0,2M),  m_part/s_part reuse wt region
  uint16_t* xb      = (uint16_t*)(ws);
  uint16_t* wt      = (uint16_t*)(ws + 16777216);
  uint16_t* h       = (uint16_t*)(ws + 18874368);
  uint16_t* z       = (uint16_t*)(ws);
  float*    m_part  = (float*)(ws + 16777216);     // 16*8192*4 = 512 KiB
  float*    s_part  = (float*)(ws + 17301504);     // 512 KiB
  uint16_t* wt2     = (uint16_t*)(ws + 35651584);  // 256 KiB [128][1024]
  float*    sums    = (float*)(ws + 35913728);     // 64 KiB: sum|sumsq
  float*    c_e     = (float*)(ws + 35979264);     // 1 KiB: c[128]|e[128]
  float*    pos_arr = (float*)(ws + 35980288);     // 32 KiB
  float*    row_loss= (float*)(ws + 36013056);     // 32 KiB

  k_conv<<<dim3(NN * HID / 1024), 256, 0, stream>>>(x, xb, sums, c_e);
  k_t1<<<dim3(32, 32), 256, 0, stream>>>(dense_w, wt, HID, HID);
  k_t2<<<dim3(PROJ / 32, HID / 32), 256, 0, stream>>>(dec_w, ln_g, ln_b, wt2,
                                                      c_e);
  k_gemm1<<<dim3(8, 128), 256, 0, stream>>>(xb, wt, dense_b, h, sums);
  k_gemm2<<<dim3(NN / 32), 256, 0, stream>>>(h, wt2, dec_b, sums, c_e, z);
  k_sim<<<dim3(NN / 256, 16), 256, 0, stream>>>(z, m_part, s_part, pos_arr);
  k_combine<<<dim3(NN / 256), 256, 0, stream>>>(m_part, s_part, pos_arr,
                                                row_loss);
  k_final<<<dim3(1), 256, 0, stream>>>(row_loss, out);
}

// Round 7
// 178.883 us; speedup vs baseline: 1.1951x; 1.1217x over previous
//
#include <hip/hip_runtime.h>
#include <math.h>
#include <stdint.h>

#define NN 8192
#define HID 1024
#define PROJ 128

constexpr float INV_T = 1.0f / 0.07f;
constexpr float LN_EPS = 1e-12f;
// exp((d-m)/T) = exp2((d-m)*CC)
constexpr float CC = 14.285714285714286f * 1.4426950408889634f;

typedef __bf16 bf16x8 __attribute__((ext_vector_type(8)));
typedef float f32x4 __attribute__((ext_vector_type(4)));

#define EXP2(x) __builtin_amdgcn_exp2f(x)

#define GLD16(g, l)                                                     \
  __builtin_amdgcn_global_load_lds(                                     \
      (const __attribute__((address_space(1))) uint32_t*)(g),           \
      (__attribute__((address_space(3))) uint32_t*)(l), 16, 0, 0)

__device__ __forceinline__ uint16_t f2bf(float f) {
  union { float f; uint32_t u; } c; c.f = f;
  uint32_t r = (c.u + 0x7FFFu + ((c.u >> 16) & 1u)) >> 16;
  return (uint16_t)r;
}
__device__ __forceinline__ float bf2f(uint16_t u) {
  union { uint32_t u; float f; } c; c.u = ((uint32_t)u) << 16;
  return c.f;
}

// gelu(v) ~= v * sigmoid(2u), u = 0.79788456(v + 0.044715 v^3)
__device__ __forceinline__ float gelu_f(float v) {
  float w = v * v;
  float u = v * fmaf(w, 0.0356774081f, 0.7978845608f);
  float e = EXP2(u * -2.8853900818f);
  return v * __builtin_amdgcn_rcpf(1.0f + e);
}

// ------------- convert fp32 -> bf16; also zero stats/c_e buffers ----------
__global__ __launch_bounds__(256) void k_conv(const float* __restrict__ in,
                                              uint16_t* __restrict__ out,
                                              float* __restrict__ sums,
                                              float* __restrict__ c_e) {
  const int b = blockIdx.x, t = threadIdx.x;
  if (b < 64) sums[b * 256 + t] = 0.f;       // sum[8192] + sumsq[8192]
  else if (b == 64) c_e[t] = 0.f;            // c[128] + e[128]
  int i = (b * 256 + t) * 4;
  float4 v = *(const float4*)(in + i);
  ushort4 o;
  o.x = f2bf(v.x); o.y = f2bf(v.y); o.z = f2bf(v.z); o.w = f2bf(v.w);
  *(ushort4*)(out + i) = o;
}

// ------------- transpose+convert: fp32 [R][C] -> bf16 [C][R] --------------
__global__ __launch_bounds__(256) void k_t1(const float* __restrict__ in,
                                            uint16_t* __restrict__ out,
                                            int R, int C) {
  __shared__ uint16_t t[32][33];
  const int cb = blockIdx.x * 32, rb = blockIdx.y * 32;
  const int tr = threadIdx.x >> 3, tc4 = (threadIdx.x & 7) * 4;
  float4 v = *(const float4*)(in + (size_t)(rb + tr) * C + cb + tc4);
  t[tc4 + 0][tr] = f2bf(v.x);
  t[tc4 + 1][tr] = f2bf(v.y);
  t[tc4 + 2][tr] = f2bf(v.z);
  t[tc4 + 3][tr] = f2bf(v.w);
  __syncthreads();
  const int oc = threadIdx.x >> 3, or4 = (threadIdx.x & 7) * 4;
  ushort4 o;
  o.x = t[oc][or4 + 0]; o.y = t[oc][or4 + 1];
  o.z = t[oc][or4 + 2]; o.w = t[oc][or4 + 3];
  *(ushort4*)(out + (size_t)(cb + oc) * R + rb + or4) = o;
}

// --- dec_w: transpose + fold gamma -> bf16 [128][1024]; column sums c,e ---
__global__ __launch_bounds__(256) void k_t2(const float* __restrict__ in,
                                            const float* __restrict__ gamma,
                                            const float* __restrict__ beta,
                                            uint16_t* __restrict__ out,
                                            float* __restrict__ c_e) {
  __shared__ float tg[32][33];
  __shared__ float tb[32][33];
  const int cb = blockIdx.x * 32, rb = blockIdx.y * 32;
  const int tr = threadIdx.x >> 3, tc4 = (threadIdx.x & 7) * 4;
  const float g = gamma[rb + tr], be = beta[rb + tr];
  float4 v = *(const float4*)(in + (size_t)(rb + tr) * PROJ + cb + tc4);
  tg[tc4 + 0][tr] = g * v.x;  tb[tc4 + 0][tr] = be * v.x;
  tg[tc4 + 1][tr] = g * v.y;  tb[tc4 + 1][tr] = be * v.y;
  tg[tc4 + 2][tr] = g * v.z;  tb[tc4 + 2][tr] = be * v.z;
  tg[tc4 + 3][tr] = g * v.w;  tb[tc4 + 3][tr] = be * v.w;
  __syncthreads();
  const int oc = threadIdx.x >> 3, or4 = (threadIdx.x & 7) * 4;
  ushort4 o;
  o.x = f2bf(tg[oc][or4 + 0]); o.y = f2bf(tg[oc][or4 + 1]);
  o.z = f2bf(tg[oc][or4 + 2]); o.w = f2bf(tg[oc][or4 + 3]);
  *(ushort4*)(out + (size_t)(cb + oc) * HID + rb + or4) = o;
  if (threadIdx.x < 32) {
    float sc = 0.f, se = 0.f;
#pragma unroll
    for (int d = 0; d < 32; ++d) { sc += tg[threadIdx.x][d]; se += tb[threadIdx.x][d]; }
    atomicAdd(c_e + cb + threadIdx.x, sc);
    atomicAdd(c_e + 128 + cb + threadIdx.x, se);
  }
}

// -------- GEMM1: h = gelu(x@W+b) bf16, + per-row sum/sumsq atomics --------
// 64x128 tile, BK=64 (two 32-k LDS panels, GLD16-compatible), grid (8,128).
__global__ __launch_bounds__(256) void k_gemm1(
    const uint16_t* __restrict__ Ab, const uint16_t* __restrict__ Bt,
    const float* __restrict__ bias, uint16_t* __restrict__ Hout,
    float* __restrict__ sums) {
  __shared__ __align__(16) uint16_t As[2 * 64 * 32];
  __shared__ __align__(16) uint16_t Bs[2 * 128 * 32];
  const int tid = threadIdx.x;
  const int bn = blockIdx.x * 128, bm = blockIdx.y * 64;
  const int wave = tid >> 6, lane = tid & 63;
  const int wx = wave & 1, wy = wave >> 1;
  const int col = lane & 15, quad = lane >> 4;
  f32x4 acc[2][4] = {};
  const char* Abase = (const char*)Ab;
  const char* Bbase = (const char*)Bt;
  for (int k0 = 0; k0 < HID; k0 += 64) {
    __syncthreads();
#pragma unroll
    for (int l = 0; l < 2; ++l) {
      int off = tid * 16 + l * 4096;
      int h = off >> 12, row = (off >> 6) & 63, inner = off & 63;
      GLD16(Abase + ((size_t)(bm + row) * HID + k0 + h * 32) * 2 + inner,
            (char*)As + off);
    }
#pragma unroll
    for (int l = 0; l < 4; ++l) {
      int off = tid * 16 + l * 4096;
      int h = off >> 13, row = (off >> 6) & 127, inner = off & 63;
      GLD16(Bbase + ((size_t)(bn + row) * HID + k0 + h * 32) * 2 + inner,
            (char*)Bs + off);
    }
    __syncthreads();
#pragma unroll
    for (int h = 0; h < 2; ++h) {
      bf16x8 a[2], b[4];
#pragma unroll
      for (int mt = 0; mt < 2; ++mt)
        a[mt] = *(const bf16x8*)&As[h * 2048 +
                                    (wy * 32 + mt * 16 + col) * 32 + quad * 8];
#pragma unroll
      for (int nt = 0; nt < 4; ++nt)
        b[nt] = *(const bf16x8*)&Bs[h * 4096 +
                                    (wx * 64 + nt * 16 + col) * 32 + quad * 8];
#pragma unroll
      for (int mt = 0; mt < 2; ++mt)
#pragma unroll
        for (int nt = 0; nt < 4; ++nt)
          acc[mt][nt] = __builtin_amdgcn_mfma_f32_16x16x32_bf16(
              a[mt], b[nt], acc[mt][nt], 0, 0, 0);
    }
  }
  float rsum[2][4] = {}, rsq[2][4] = {};
#pragma unroll
  for (int nt = 0; nt < 4; ++nt) {
    int gj = bn + wx * 64 + nt * 16 + col;
    float bv = bias[gj];
#pragma unroll
    for (int mt = 0; mt < 2; ++mt)
#pragma unroll
      for (int r = 0; r < 4; ++r) {
        int gi = bm + wy * 32 + mt * 16 + quad * 4 + r;
        float gl = gelu_f(acc[mt][nt][r] + bv);
        Hout[(size_t)gi * HID + gj] = f2bf(gl);
        rsum[mt][r] += gl;
        rsq[mt][r] = fmaf(gl, gl, rsq[mt][r]);
      }
  }
#pragma unroll
  for (int mt = 0; mt < 2; ++mt)
#pragma unroll
    for (int r = 0; r < 4; ++r) {
      float s1 = rsum[mt][r], s2 = rsq[mt][r];
#pragma unroll
      for (int off = 1; off < 16; off <<= 1) {
        s1 += __shfl_xor(s1, off, 64);
        s2 += __shfl_xor(s2, off, 64);
      }
      if (col == 0) {
        int gi = bm + wy * 32 + mt * 16 + quad * 4 + r;
        atomicAdd(&sums[gi], s1);
        atomicAdd(&sums[NN + gi], s2);
      }
    }
}

// --- GEMM2 with LN folded: z = r*(h@Wg) - r*mu*c + e + dec_b, bf16 out ----
__global__ __launch_bounds__(256) void k_gemm2(
    const uint16_t* __restrict__ Hb, const uint16_t* __restrict__ Wt2,
    const float* __restrict__ bd, const float* __restrict__ sums,
    const float* __restrict__ c_e, uint16_t* __restrict__ Z) {
  __shared__ __align__(16) uint16_t As2[32 * 32];
  __shared__ __align__(16) uint16_t Bs2[128 * 32];
  __shared__ float muS[32], rS[32];
  const int tid = threadIdx.x;
  const int bm = blockIdx.x * 32;
  const int wave = tid >> 6, lane = tid & 63;
  const int wx = wave & 1, wy = wave >> 1;
  const int col = lane & 15, quad = lane >> 4;
  if (tid < 32) {
    float s = sums[bm + tid], q = sums[NN + bm + tid];
    float mu = s * (1.0f / HID);
    float var = q * (1.0f / HID) - mu * mu;
    muS[tid] = mu;
    rS[tid] = rsqrtf(var + LN_EPS);
  }
  f32x4 acc[4] = {};
  const char* Abase = (const char*)Hb;
  const char* Bbase = (const char*)Wt2;
  for (int k0 = 0; k0 < HID; k0 += 32) {
    __syncthreads();
    if (tid < 128) {
      int off = tid * 16;
      int row = off >> 6, inner = off & 63;
      GLD16(Abase + ((size_t)(bm + row) * HID + k0) * 2 + inner,
            (char*)As2 + off);
    }
#pragma unroll
    for (int l = 0; l < 2; ++l) {
      int off = tid * 16 + l * 4096;
      int row = off >> 6, inner = off & 63;
      GLD16(Bbase + ((size_t)row * HID + k0) * 2 + inner, (char*)Bs2 + off);
    }
    __syncthreads();
    bf16x8 a = *(const bf16x8*)&As2[(wy * 16 + col) * 32 + quad * 8];
#pragma unroll
    for (int nt = 0; nt < 4; ++nt) {
      bf16x8 b = *(const bf16x8*)&Bs2[(wx * 64 + nt * 16 + col) * 32 + quad * 8];
      acc[nt] = __builtin_amdgcn_mfma_f32_16x16x32_bf16(a, b, acc[nt], 0, 0, 0);
    }
  }
#pragma unroll
  for (int nt = 0; nt < 4; ++nt) {
    int gj = wx * 64 + nt * 16 + col;
    float ck = c_e[gj], ek = c_e[128 + gj] + bd[gj];
#pragma unroll
    for (int r = 0; r < 4; ++r) {
      int li = wy * 16 + quad * 4 + r;
      float mu = muS[li], rr = rS[li];
      float z = fmaf(rr, acc[nt][r], fmaf(-rr * mu, ck, ek));
      Z[(size_t)(bm + li) * PROJ + gj] = f2bf(z);
    }
  }
}

// ------ flash logsumexp over Z Z^T: block-shared LDS j-tiles --------------
// Block = 4 waves x 32 i-rows = 128 i (fits registers: afr 32 + acc 32 +
// ms/ss 16 + b 16 ~= 115 VGPR, no spills). j staged 64x128 (16 KB) in LDS,
// XOR-swizzled for conflict-light ds_read_b128. Double-buffered, one
// barrier per tile. grid (64, 16): chunk = 512 j.
__device__ __forceinline__ void lse4(float& m, float& s, float v0, float v1,
                                     float v2, float v3) {
  float lm = fmaxf(fmaxf(v0, v1), fmaxf(v2, v3));
  float mn = fmaxf(m, lm);
  float tn = mn * CC;
  float rs = EXP2(fmaf(m, CC, -tn));
  float e = EXP2(fmaf(v0, CC, -tn)) + EXP2(fmaf(v1, CC, -tn)) +
            EXP2(fmaf(v2, CC, -tn)) + EXP2(fmaf(v3, CC, -tn));
  s = fmaf(s, rs, e);
  m = mn;
}

__global__ __launch_bounds__(256) void k_sim(const uint16_t* __restrict__ Z,
                                             float* __restrict__ m_part,
                                             float* __restrict__ s_part,
                                             float* __restrict__ pos_arr) {
  __shared__ __align__(16) uint16_t Bsh[2][64 * 128];
  const int tid = threadIdx.x;
  const int wave = tid >> 6, lane = tid & 63;
  const int col = lane & 15, quad = lane >> 4;
  const int wrow0 = blockIdx.x * 128 + wave * 32;
  const int chunk = blockIdx.y;
  const char* Zb = (const char*)Z;

  // A fragments: 32 i-rows per wave, K=128, in registers (32 VGPRs)
  bf16x8 afr[2][4];
#pragma unroll
  for (int mt = 0; mt < 2; ++mt)
#pragma unroll
    for (int kc = 0; kc < 4; ++kc)
      afr[mt][kc] = *(const bf16x8*)(Z +
          (size_t)(wrow0 + mt * 16 + col) * PROJ + kc * 32 + quad * 8);

  float ms[8], ss[8];
#pragma unroll
  for (int i = 0; i < 8; ++i) { ms[i] = -INFINITY; ss[i] = 0.f; }

  const int diag_t = wrow0 & ~63;
  const int pos_t = ((wrow0 + NN / 2) & (NN - 1)) & ~63;
  const int jbase = chunk * 512;

  // stage tile t into buffer buf; source chunk XOR-swizzled by row&7
#define STAGE(t, bufv)                                                      \
  {                                                                         \
    const int j0s = jbase + (t) * 64;                                       \
    _Pragma("unroll") for (int l = 0; l < 4; ++l) {                         \
      int off = tid * 16 + l * 4096;                                        \
      int row = off >> 8;                                                   \
      int p = (off >> 4) & 15;                                              \
      GLD16(Zb + (size_t)(j0s + row) * 256 + ((p ^ (row & 7)) << 4),        \
            (char*)&Bsh[bufv][0] + off);                                    \
    }                                                                       \
  }

  STAGE(0, 0);
  for (int t = 0; t < 8; ++t) {
    const int buf = t & 1;
    __syncthreads();   // staging of tile t landed; all waves done with buf
    if (t < 7) STAGE(t + 1, buf ^ 1);
    const int jt = jbase + t * 64;
    f32x4 acc[2][4] = {};
#pragma unroll
    for (int kc = 0; kc < 4; ++kc) {
      bf16x8 b[4];
#pragma unroll
      for (int nt = 0; nt < 4; ++nt) {
        int r = nt * 16 + col;
        b[nt] = *(const bf16x8*)&Bsh[buf][r * 128 +
                                         (((kc * 4 + quad) ^ (col & 7)) << 3)];
      }
#pragma unroll
      for (int mt = 0; mt < 2; ++mt)
#pragma unroll
        for (int nt = 0; nt < 4; ++nt)
          acc[mt][nt] = __builtin_amdgcn_mfma_f32_16x16x32_bf16(
              afr[mt][kc], b[nt], acc[mt][nt], 0, 0, 0);
    }
    if (jt != diag_t && jt != pos_t) {
#pragma unroll
      for (int mt = 0; mt < 2; ++mt)
#pragma unroll
        for (int r = 0; r < 4; ++r)
          lse4(ms[mt * 4 + r], ss[mt * 4 + r], acc[mt][0][r], acc[mt][1][r],
               acc[mt][2][r], acc[mt][3][r]);
    } else {
      const bool isd = (jt == diag_t);
#pragma unroll
      for (int mt = 0; mt < 2; ++mt)
#pragma unroll
        for (int r = 0; r < 4; ++r) {
          int gi = wrow0 + mt * 16 + quad * 4 + r;
          int partner = (gi + NN / 2) & (NN - 1);
          float v[4];
#pragma unroll
          for (int nt = 0; nt < 4; ++nt) {
            int gj = jt + nt * 16 + col;
            float d = acc[mt][nt][r];
            if (!isd && gj == partner) pos_arr[gi] = d;
            v[nt] = (isd && gj == gi) ? -INFINITY : d;
          }
          lse4(ms[mt * 4 + r], ss[mt * 4 + r], v[0], v[1], v[2], v[3]);
        }
    }
  }
#undef STAGE
  // reduce (m,s) across the 16 col-lanes sharing the same rows
#pragma unroll
  for (int ri = 0; ri < 8; ++ri) {
#pragma unroll
    for (int off = 1; off < 16; off <<= 1) {
      float om = __shfl_xor(ms[ri], off, 64);
      float os = __shfl_xor(ss[ri], off, 64);
      float mn = fmaxf(ms[ri], om);
      float tn = mn * CC;
      ss[ri] = fmaf(ss[ri], EXP2(fmaf(ms[ri], CC, -tn)),
                    os * EXP2(fmaf(om, CC, -tn)));
      ms[ri] = mn;
    }
  }
  if (col == 0) {
#pragma unroll
    for (int ri = 0; ri < 8; ++ri) {
      int gi = wrow0 + (ri >> 2) * 16 + quad * 4 + (ri & 3);
      m_part[(size_t)chunk * NN + gi] = ms[ri];
      s_part[(size_t)chunk * NN + gi] = ss[ri];
    }
  }
}

// ---------------- combine 16 chunk-partials per row ----------------
__global__ __launch_bounds__(256) void k_combine(
    const float* __restrict__ m_part, const float* __restrict__ s_part,
    const float* __restrict__ pos_arr, float* __restrict__ row_loss) {
  const int i = blockIdx.x * 256 + threadIdx.x;
  float M = -INFINITY;
#pragma unroll
  for (int p = 0; p < 16; ++p) M = fmaxf(M, m_part[(size_t)p * NN + i]);
  float S = 0.f;
  float t = M * CC;
#pragma unroll
  for (int p = 0; p < 16; ++p)
    S += s_part[(size_t)p * NN + i] * EXP2(fmaf(m_part[(size_t)p * NN + i], CC, -t));
  row_loss[i] = (M - pos_arr[i]) * INV_T + logf(S);
}

// ---------------- mean over rows ----------------
__global__ __launch_bounds__(256) void k_final(
    const float* __restrict__ row_loss, float* __restrict__ out) {
  const int tid = threadIdx.x;
  float s = 0.f;
#pragma unroll
  for (int l = 0; l < 32; ++l) s += row_loss[tid + l * 256];
#pragma unroll
  for (int off = 32; off > 0; off >>= 1) s += __shfl_down(s, off);
  __shared__ float red[4];
  const int wave = tid >> 6, lane = tid & 63;
  if (lane == 0) red[wave] = s;
  __syncthreads();
  if (tid == 0) out[0] = (red[0] + red[1] + red[2] + red[3]) * (1.0f / NN);
}

extern "C" void kernel_launch(void* const* d_in, const int* in_sizes, int n_in,
                              void* d_out, int out_size, void* d_ws,
                              size_t ws_size, hipStream_t stream) {
  const float* x       = (const float*)d_in[0];
  const float* dense_w = (const float*)d_in[1];
  const float* dense_b = (const float*)d_in[2];
  const float* ln_g    = (const float*)d_in[3];
  const float* ln_b    = (const float*)d_in[4];
  const float* dec_w   = (const float*)d_in[5];
  const float* dec_b   = (const float*)d_in[6];
  float* out = (float*)d_out;
  char* ws = (char*)d_ws;
  // Phase 1 (through gemm1): xb [0,16M), wt [16M,18M), h [18M,34M)
  // Phase 2 (after gemm1):   z  [0,2M),  m_part/s_part reuse wt region
  uint16_t* xb      = (uint16_t*)(ws);
  uint16_t* wt      = (uint16_t*)(ws + 16777216);
  uint16_t* h       = (uint16_t*)(ws + 18874368);
  uint16_t* z       = (uint16_t*)(ws);
  float*    m_part  = (float*)(ws + 16777216);     // 16*8192*4 = 512 KiB
  float*    s_part  = (float*)(ws + 17301504);     // 512 KiB
  uint16_t* wt2     = (uint16_t*)(ws + 35651584);  // 256 KiB [128][1024]
  float*    sums    = (float*)(ws + 35913728);     // 64 KiB: sum|sumsq
  float*    c_e     = (float*)(ws + 35979264);     // 1 KiB: c[128]|e[128]
  float*    pos_arr = (float*)(ws + 35980288);     // 32 KiB
  float*    row_loss= (float*)(ws + 36013056);     // 32 KiB

  k_conv<<<dim3(NN * HID / 1024), 256, 0, stream>>>(x, xb, sums, c_e);
  k_t1<<<dim3(32, 32), 256, 0, stream>>>(dense_w, wt, HID, HID);
  k_t2<<<dim3(PROJ / 32, HID / 32), 256, 0, stream>>>(dec_w, ln_g, ln_b, wt2,
                                                      c_e);
  k_gemm1<<<dim3(8, 128), 256, 0, stream>>>(xb, wt, dense_b, h, sums);
  k_gemm2<<<dim3(NN / 32), 256, 0, stream>>>(h, wt2, dec_b, sums, c_e, z);
  k_sim<<<dim3(NN / 128, 16), 256, 0, stream>>>(z, m_part, s_part, pos_arr);
  k_combine<<<dim3(NN / 256), 256, 0, stream>>>(m_part, s_part, pos_arr,
                                                row_loss);
  k_final<<<dim3(1), 256, 0, stream>>>(row_loss, out);
}